// Round 16
// baseline (2786.462 us; speedup 1.0000x reference)
//
#include <hip/hip_runtime.h>
#include <math.h>

#define NT 2048
#define HS 64
#define HNN 256
#define NSTEPS 1000
#define TSTEP 0.01f

typedef unsigned short u16;
typedef __attribute__((ext_vector_type(8))) short bf16x8;
typedef __attribute__((ext_vector_type(4))) float f32x4;

// ws: only the bf16 frag region is used
#define OFF_HT   148736    // YH (65536 floats worth) + YL

#define ST_W 260           // stage stride (floats): 16 rows x 260, x2 buffers

// RNE f32 -> bf16 split: x ~= hi + lo (each bf16), err ~ 2^-18 |x|
__device__ inline void bsplit(float x, u16& hi, u16& lo) {
    unsigned u = __float_as_uint(x);
    unsigned r = (u + 0x7FFFu + ((u >> 16) & 1u)) >> 16;
    hi = (u16)r;
    float xh = __uint_as_float(r << 16);
    float d = x - xh;
    unsigned v = __float_as_uint(d);
    unsigned s = (v + 0x7FFFu + ((v >> 16) & 1u)) >> 16;
    lo = (u16)s;
}

__device__ inline void bar_lds() {
    asm volatile("s_waitcnt lgkmcnt(0)" ::: "memory");
    __builtin_amdgcn_s_barrier();
    asm volatile("" ::: "memory");
}

__device__ inline float tanh_fast(float x) {
    float xc = fminf(fmaxf(x, -15.f), 15.f);
    float a = __builtin_amdgcn_exp2f(xc * 2.885390082f);   // e^{2x}
    return (a - 1.f) * __builtin_amdgcn_rcpf(a + 1.f);
}

// ---------------- k_front: 256 blocks x 512 thr, 8 cols/block (round-14 exact) ---
struct FrontSh {
    float Aug[64 * 73];        // [P | x0] 18.7 KB
    float shT[256 * 9];        // hT for 8 cols
    float y0s[64 * 9];
    float fvec[2][64];
    float tgt[8][2];
    float lam_s[64], l2l_s[64];
    float Q_s[128];
    float us[8 * 128];
};

__global__ __launch_bounds__(512) void k_front(const float* __restrict__ target,
                                               const float* __restrict__ l1_w,
                                               const float* __restrict__ l1_b,
                                               const float* __restrict__ l2_w,
                                               const float* __restrict__ l2_b,
                                               const float* __restrict__ lm_w,
                                               const float* __restrict__ lm_b,
                                               const float* __restrict__ D,
                                               const float* __restrict__ P,
                                               float* __restrict__ ws,
                                               float* __restrict__ actions) {
    __shared__ FrontSh sh;
    int ct = blockIdx.x;                 // 0..255
    int cbase = ct * 8;
    int tid = threadIdx.x;

    for (int idx = tid; idx < 4096; idx += 512) {
        int r = idx >> 6, c = idx & 63;
        sh.Aug[r * 73 + c] = P[r * 64 + c];
    }
    if (tid >= 448 && tid < 456) {
        int c = tid - 448;
        float2 tv = ((const float2*)target)[cbase + c];
        sh.tgt[c][0] = tv.x; sh.tgt[c][1] = tv.y;
    } else if (tid >= 256 && tid < 320) {
        int i = tid - 256;
        float l = 1.0f - TSTEP * expf(D[i]);
        sh.lam_s[i] = l;
        sh.l2l_s[i] = log2f(l);
    } else if (tid >= 320 && tid < 448) {
        int t = tid - 320;
        int a = t >> 6, i = t & 63;
        float s = 0.f;
        for (int r = 0; r < 64; ++r) s = fmaf(lm_w[a * 64 + r], P[r * 64 + i], s);
        sh.Q_s[t] = s;
    }
    __syncthreads();

    if (tid < 256) {
        float w0 = l1_w[2 * tid], w1 = l1_w[2 * tid + 1], bb = l1_b[tid];
        #pragma unroll
        for (int cc = 0; cc < 8; ++cc)
            sh.shT[tid * 9 + cc] =
                fmaxf(fmaf(w0, sh.tgt[cc][0], fmaf(w1, sh.tgt[cc][1], bb)), 0.f);
    }
    __syncthreads();

    int i = tid >> 3, c = tid & 7;
    {   // x0 -> Aug cols 64..71
        const float* l2wi = l2_w + i * 256;
        float a0 = l2_b[i], a1 = 0, a2 = 0, a3 = 0;
        #pragma unroll 4
        for (int j = 0; j < 256; j += 4) {
            a0 = fmaf(l2wi[j],     sh.shT[j * 9 + c],       a0);
            a1 = fmaf(l2wi[j + 1], sh.shT[(j + 1) * 9 + c], a1);
            a2 = fmaf(l2wi[j + 2], sh.shT[(j + 2) * 9 + c], a2);
            a3 = fmaf(l2wi[j + 3], sh.shT[(j + 3) * 9 + c], a3);
        }
        sh.Aug[i * 73 + 64 + c] = (a0 + a1) + (a2 + a3);
    }
    if (tid < 64) {
        float nv = sh.Aug[tid * 73];
        float pv = __shfl(nv, 0);
        sh.fvec[0][tid] = (tid == 0) ? 0.f : nv * __builtin_amdgcn_rcpf(pv);
    }
    __syncthreads();

    for (int t = 0; t < 64; ++t) {
        int par = t & 1;
        if (tid < 64) {
            int col0 = (t < 63) ? (t + 1) : 64;
            float f = sh.fvec[par][tid];
            float src = sh.Aug[t * 73 + col0];
            float nv = sh.Aug[tid * 73 + col0] - f * src;
            sh.Aug[tid * 73 + col0] = nv;
            if (t < 63) {
                float pv = __shfl(nv, t + 1);
                sh.fvec[par ^ 1][tid] = (tid == (t + 1)) ? 0.f
                                        : nv * __builtin_amdgcn_rcpf(pv);
            }
        } else {
            int w = (tid >> 6) - 1;
            int lane = tid & 63;
            float f = sh.fvec[par][lane];
            const float* rowp = sh.Aug + t * 73;
            float* rowr = sh.Aug + lane * 73;
            int pcnt = 62 - t;
            int smax = pcnt + 8;
            for (int s = 1 + w; s <= smax; s += 7) {
                int col = (s <= pcnt) ? (t + 1 + s) : (64 + (s - pcnt - 1));
                rowr[col] -= f * rowp[col];
            }
        }
        __syncthreads();
    }

    sh.y0s[i * 9 + c] = sh.Aug[i * 73 + 64 + c]
                        * __builtin_amdgcn_rcpf(sh.Aug[i * 73 + i]);
    __syncthreads();

    for (int idx = tid; idx < 1024; idx += 512) {
        int cgi = idx >> 7, t = idx & 127;
        sh.us[cgi * 128 + t] = sh.Q_s[t] * sh.y0s[(t & 63) * 9 + cgi];
    }
    if (tid < 128) {
        int kt = tid >> 6, lane = tid & 63;
        int c15 = lane & 15;
        if ((c15 >> 3) == (ct & 1)) {
            int cl = c15 & 7;
            int i0 = kt * 32 + (lane >> 4) * 8;
            u16* YH = (u16*)(ws + OFF_HT);
            u16* YL = YH + 131072;
            bf16x8 vh, vl;
            #pragma unroll
            for (int j = 0; j < 8; ++j) {
                u16 h, lo;
                bsplit(sh.y0s[(i0 + j) * 9 + cl], h, lo);
                vh[j] = (short)h; vl[j] = (short)lo;
            }
            int off = (((ct >> 1) * 2 + kt) * 64 + lane);
            *(bf16x8*)(YH + off * 8) = vh;
            *(bf16x8*)(YL + off * 8) = vl;
        }
    }
    __syncthreads();

    if (tid < 500) {
        int k0 = tid * 2;
        float b0 = lm_b[0], b1 = lm_b[1];
        float fk0 = (float)k0;
        float2 s[8][2];
        #pragma unroll
        for (int j = 0; j < 8; ++j) {
            s[j][0] = make_float2(b0, b0);
            s[j][1] = make_float2(b1, b1);
        }
        #pragma unroll 2
        for (int ii = 0; ii < 64; ++ii) {
            float p0 = __builtin_amdgcn_exp2f(fk0 * sh.l2l_s[ii]);
            float p1 = p0 * sh.lam_s[ii];
            #pragma unroll
            for (int j = 0; j < 8; ++j) {
                float u0 = sh.us[j * 128 + ii];
                float u1 = sh.us[j * 128 + 64 + ii];
                s[j][0].x = fmaf(u0, p0, s[j][0].x);
                s[j][0].y = fmaf(u0, p1, s[j][0].y);
                s[j][1].x = fmaf(u1, p0, s[j][1].x);
                s[j][1].y = fmaf(u1, p1, s[j][1].y);
            }
        }
        #pragma unroll
        for (int j = 0; j < 8; ++j)
            #pragma unroll
            for (int a = 0; a < 2; ++a) {
                float2 r;
                r.x = tanh_fast(s[j][a].x);
                r.y = tanh_fast(s[j][a].y);
                *(float2*)(actions + (size_t)(cbase + j) * 2000 + a * 1000 + k0) = r;
            }
    }
}

// ---------------- main: hidden[k] = (P diag(lam^k)) @ y0 --------------------------
// WAVE-SPECIALIZED: waves 0-3 compute (MFMA + ds_write, no global stores -> clean
// vmcnt), waves 4-7 store (ds_read + global_store, never vmcnt-waited -> continuous
// store stream). Double-buffered 16x260 stage; ONE barrier per phase; 32 phases
// (8 col-groups x 4 row-tiles). Buffers alternate: dump(p-1) runs parallel with
// compute(p) -- write(p)/dump(p+1) on a buffer are always barrier-separated.
__global__ __launch_bounds__(512, 2) void k_hidden(const float* __restrict__ P,
                                                   const float* __restrict__ D,
                                                   const float* __restrict__ ws,
                                                   float* __restrict__ hidden) {
    int k = blockIdx.x;
    int tid = threadIdx.x;
    int wid = tid >> 6, lane = tid & 63;
    int l15 = lane & 15, lg = lane >> 4;

    __shared__ float stage[2][16 * ST_W];   // 2 x 16.6 KB
    __shared__ float lp_s[64];

    const u16* YH = (const u16*)(ws + OFF_HT);
    const u16* YL = YH + 131072;

    if (tid < 64) {
        float l = 1.0f - TSTEP * expf(D[tid]);
        lp_s[tid] = exp2f((float)k * log2f(l));
    }
    __syncthreads();

    float* outk = hidden + (size_t)k * 64 * NT;

    if (wid < 4) {
        // ---------------- compute waves ----------------
        bf16x8 ah[4][2], al[4][2];
        #pragma unroll
        for (int rt = 0; rt < 4; ++rt) {
            int r = rt * 16 + l15;
            #pragma unroll
            for (int kt = 0; kt < 2; ++kt) {
                int i0 = kt * 32 + lg * 8;
                #pragma unroll
                for (int j = 0; j < 8; ++j) {
                    float v = P[r * 64 + i0 + j] * lp_s[i0 + j];
                    u16 h, lo;
                    bsplit(v, h, lo);
                    ah[rt][kt][j] = (short)h;
                    al[rt][kt][j] = (short)lo;
                }
            }
        }
        bf16x8 bh[4][2], bl[4][2];
        #pragma unroll 1
        for (int p = 0; p < 32; ++p) {
            int cg = p >> 2, rt = p & 3;
            if (rt == 0) {
                // load B frags for this col-group (L2-hot; waits touch only B)
                #pragma unroll
                for (int q = 0; q < 4; ++q)
                    #pragma unroll
                    for (int kt = 0; kt < 2; ++kt) {
                        int ct_g = cg * 16 + wid * 4 + q;
                        int off = ((ct_g * 2 + kt) * 64 + lane) * 8;
                        bh[q][kt] = *(const bf16x8*)(YH + off);
                        bl[q][kt] = *(const bf16x8*)(YL + off);
                    }
            }
            float* buf = stage[p & 1];
            #pragma unroll
            for (int q = 0; q < 4; ++q) {
                f32x4 acc = {0.f, 0.f, 0.f, 0.f};
                #pragma unroll
                for (int kt = 0; kt < 2; ++kt) {
                    acc = __builtin_amdgcn_mfma_f32_16x16x32_bf16(ah[rt][kt], bh[q][kt], acc, 0, 0, 0);
                    acc = __builtin_amdgcn_mfma_f32_16x16x32_bf16(al[rt][kt], bh[q][kt], acc, 0, 0, 0);
                    acc = __builtin_amdgcn_mfma_f32_16x16x32_bf16(ah[rt][kt], bl[q][kt], acc, 0, 0, 0);
                }
                int col = wid * 64 + q * 16 + l15;
                #pragma unroll
                for (int reg = 0; reg < 4; ++reg)
                    buf[(lg * 4 + reg) * ST_W + col] = acc[reg];
            }
            bar_lds();
        }
        // store waves handle the final dump; compute waves exit
    } else {
        // ---------------- store waves ----------------
        int sw = wid - 4;
        #pragma unroll 1
        for (int p = 0; p < 32; ++p) {
            if (p > 0) {
                int pd = p - 1, cg = pd >> 2, rt = pd & 3;
                const float* buf = stage[pd & 1];
                #pragma unroll
                for (int r4 = 0; r4 < 4; ++r4) {
                    int row = sw * 4 + r4;
                    f32x4 v = *(const f32x4*)&buf[row * ST_W + lane * 4];
                    *(f32x4*)(outk + (size_t)(rt * 16 + row) * NT + cg * 256 + lane * 4) = v;
                }
            }
            bar_lds();
        }
        {   // epilogue: dump phase 31 (buf 1, cg 7, rt 3)
            const float* buf = stage[1];
            #pragma unroll
            for (int r4 = 0; r4 < 4; ++r4) {
                int row = sw * 4 + r4;
                f32x4 v = *(const f32x4*)&buf[row * ST_W + lane * 4];
                *(f32x4*)(outk + (size_t)(48 + row) * NT + 7 * 256 + lane * 4) = v;
            }
        }
    }
}

extern "C" void kernel_launch(void* const* d_in, const int* in_sizes, int n_in,
                              void* d_out, int out_size, void* d_ws, size_t ws_size,
                              hipStream_t stream) {
    const float* target = (const float*)d_in[0];
    const float* D      = (const float*)d_in[1];
    const float* P      = (const float*)d_in[2];
    const float* l1_w   = (const float*)d_in[3];
    const float* l1_b   = (const float*)d_in[4];
    const float* l2_w   = (const float*)d_in[5];
    const float* l2_b   = (const float*)d_in[6];
    const float* lm_w   = (const float*)d_in[7];
    const float* lm_b   = (const float*)d_in[8];
    float* ws = (float*)d_ws;
    float* actions = (float*)d_out;                  // 2048*2*1000
    float* hidden  = (float*)d_out + 4096000;        // 1000*64*2048

    hipLaunchKernelGGL(k_front,  dim3(256),  dim3(512), 0, stream,
                       target, l1_w, l1_b, l2_w, l2_b, lm_w, lm_b, D, P, ws, actions);
    hipLaunchKernelGGL(k_hidden, dim3(1000), dim3(512), 0, stream, P, D, ws, hidden);
}

// Round 17
// 186.240 us; speedup vs baseline: 14.9617x; 14.9617x over previous
//
#include <hip/hip_runtime.h>
#include <math.h>

#define NT 2048
#define HS 64
#define HNN 256
#define NSTEPS 1000
#define TSTEP 0.01f

typedef unsigned short u16;
typedef __attribute__((ext_vector_type(8))) short bf16x8;
typedef __attribute__((ext_vector_type(4))) float f32x4;

// ws: only the bf16 frag region is used
#define OFF_HT   148736    // YH (65536 floats worth) + YL

#define ST_W 260           // stage stride (floats): 16 rows x 260, x2 buffers

// RNE f32 -> bf16 split: x ~= hi + lo (each bf16), err ~ 2^-18 |x|
__device__ inline void bsplit(float x, u16& hi, u16& lo) {
    unsigned u = __float_as_uint(x);
    unsigned r = (u + 0x7FFFu + ((u >> 16) & 1u)) >> 16;
    hi = (u16)r;
    float xh = __uint_as_float(r << 16);
    float d = x - xh;
    unsigned v = __float_as_uint(d);
    unsigned s = (v + 0x7FFFu + ((v >> 16) & 1u)) >> 16;
    lo = (u16)s;
}

__device__ inline void bar_lds() {
    asm volatile("s_waitcnt lgkmcnt(0)" ::: "memory");
    __builtin_amdgcn_s_barrier();
    asm volatile("" ::: "memory");
}

__device__ inline float tanh_fast(float x) {
    float xc = fminf(fmaxf(x, -15.f), 15.f);
    float a = __builtin_amdgcn_exp2f(xc * 2.885390082f);   // e^{2x}
    return (a - 1.f) * __builtin_amdgcn_rcpf(a + 1.f);
}

// ---------------- k_front: 256 blocks x 512 thr, 8 cols/block (round-14 exact) ---
struct FrontSh {
    float Aug[64 * 73];        // [P | x0] 18.7 KB
    float shT[256 * 9];        // hT for 8 cols
    float y0s[64 * 9];
    float fvec[2][64];
    float tgt[8][2];
    float lam_s[64], l2l_s[64];
    float Q_s[128];
    float us[8 * 128];
};

__global__ __launch_bounds__(512) void k_front(const float* __restrict__ target,
                                               const float* __restrict__ l1_w,
                                               const float* __restrict__ l1_b,
                                               const float* __restrict__ l2_w,
                                               const float* __restrict__ l2_b,
                                               const float* __restrict__ lm_w,
                                               const float* __restrict__ lm_b,
                                               const float* __restrict__ D,
                                               const float* __restrict__ P,
                                               float* __restrict__ ws,
                                               float* __restrict__ actions) {
    __shared__ FrontSh sh;
    int ct = blockIdx.x;                 // 0..255
    int cbase = ct * 8;
    int tid = threadIdx.x;

    for (int idx = tid; idx < 4096; idx += 512) {
        int r = idx >> 6, c = idx & 63;
        sh.Aug[r * 73 + c] = P[r * 64 + c];
    }
    if (tid >= 448 && tid < 456) {
        int c = tid - 448;
        float2 tv = ((const float2*)target)[cbase + c];
        sh.tgt[c][0] = tv.x; sh.tgt[c][1] = tv.y;
    } else if (tid >= 256 && tid < 320) {
        int i = tid - 256;
        float l = 1.0f - TSTEP * expf(D[i]);
        sh.lam_s[i] = l;
        sh.l2l_s[i] = log2f(l);
    } else if (tid >= 320 && tid < 448) {
        int t = tid - 320;
        int a = t >> 6, i = t & 63;
        float s = 0.f;
        for (int r = 0; r < 64; ++r) s = fmaf(lm_w[a * 64 + r], P[r * 64 + i], s);
        sh.Q_s[t] = s;
    }
    __syncthreads();

    if (tid < 256) {
        float w0 = l1_w[2 * tid], w1 = l1_w[2 * tid + 1], bb = l1_b[tid];
        #pragma unroll
        for (int cc = 0; cc < 8; ++cc)
            sh.shT[tid * 9 + cc] =
                fmaxf(fmaf(w0, sh.tgt[cc][0], fmaf(w1, sh.tgt[cc][1], bb)), 0.f);
    }
    __syncthreads();

    int i = tid >> 3, c = tid & 7;
    {   // x0 -> Aug cols 64..71
        const float* l2wi = l2_w + i * 256;
        float a0 = l2_b[i], a1 = 0, a2 = 0, a3 = 0;
        #pragma unroll 4
        for (int j = 0; j < 256; j += 4) {
            a0 = fmaf(l2wi[j],     sh.shT[j * 9 + c],       a0);
            a1 = fmaf(l2wi[j + 1], sh.shT[(j + 1) * 9 + c], a1);
            a2 = fmaf(l2wi[j + 2], sh.shT[(j + 2) * 9 + c], a2);
            a3 = fmaf(l2wi[j + 3], sh.shT[(j + 3) * 9 + c], a3);
        }
        sh.Aug[i * 73 + 64 + c] = (a0 + a1) + (a2 + a3);
    }
    if (tid < 64) {
        float nv = sh.Aug[tid * 73];
        float pv = __shfl(nv, 0);
        sh.fvec[0][tid] = (tid == 0) ? 0.f : nv * __builtin_amdgcn_rcpf(pv);
    }
    __syncthreads();

    for (int t = 0; t < 64; ++t) {
        int par = t & 1;
        if (tid < 64) {
            int col0 = (t < 63) ? (t + 1) : 64;
            float f = sh.fvec[par][tid];
            float src = sh.Aug[t * 73 + col0];
            float nv = sh.Aug[tid * 73 + col0] - f * src;
            sh.Aug[tid * 73 + col0] = nv;
            if (t < 63) {
                float pv = __shfl(nv, t + 1);
                sh.fvec[par ^ 1][tid] = (tid == (t + 1)) ? 0.f
                                        : nv * __builtin_amdgcn_rcpf(pv);
            }
        } else {
            int w = (tid >> 6) - 1;
            int lane = tid & 63;
            float f = sh.fvec[par][lane];
            const float* rowp = sh.Aug + t * 73;
            float* rowr = sh.Aug + lane * 73;
            int pcnt = 62 - t;
            int smax = pcnt + 8;
            for (int s = 1 + w; s <= smax; s += 7) {
                int col = (s <= pcnt) ? (t + 1 + s) : (64 + (s - pcnt - 1));
                rowr[col] -= f * rowp[col];
            }
        }
        __syncthreads();
    }

    sh.y0s[i * 9 + c] = sh.Aug[i * 73 + 64 + c]
                        * __builtin_amdgcn_rcpf(sh.Aug[i * 73 + i]);
    __syncthreads();

    for (int idx = tid; idx < 1024; idx += 512) {
        int cgi = idx >> 7, t = idx & 127;
        sh.us[cgi * 128 + t] = sh.Q_s[t] * sh.y0s[(t & 63) * 9 + cgi];
    }
    if (tid < 128) {
        int kt = tid >> 6, lane = tid & 63;
        int c15 = lane & 15;
        if ((c15 >> 3) == (ct & 1)) {
            int cl = c15 & 7;
            int i0 = kt * 32 + (lane >> 4) * 8;
            u16* YH = (u16*)(ws + OFF_HT);
            u16* YL = YH + 131072;
            bf16x8 vh, vl;
            #pragma unroll
            for (int j = 0; j < 8; ++j) {
                u16 h, lo;
                bsplit(sh.y0s[(i0 + j) * 9 + cl], h, lo);
                vh[j] = (short)h; vl[j] = (short)lo;
            }
            int off = (((ct >> 1) * 2 + kt) * 64 + lane);
            *(bf16x8*)(YH + off * 8) = vh;
            *(bf16x8*)(YL + off * 8) = vl;
        }
    }
    __syncthreads();

    if (tid < 500) {
        int k0 = tid * 2;
        float b0 = lm_b[0], b1 = lm_b[1];
        float fk0 = (float)k0;
        float2 s[8][2];
        #pragma unroll
        for (int j = 0; j < 8; ++j) {
            s[j][0] = make_float2(b0, b0);
            s[j][1] = make_float2(b1, b1);
        }
        #pragma unroll 2
        for (int ii = 0; ii < 64; ++ii) {
            float p0 = __builtin_amdgcn_exp2f(fk0 * sh.l2l_s[ii]);
            float p1 = p0 * sh.lam_s[ii];
            #pragma unroll
            for (int j = 0; j < 8; ++j) {
                float u0 = sh.us[j * 128 + ii];
                float u1 = sh.us[j * 128 + 64 + ii];
                s[j][0].x = fmaf(u0, p0, s[j][0].x);
                s[j][0].y = fmaf(u0, p1, s[j][0].y);
                s[j][1].x = fmaf(u1, p0, s[j][1].x);
                s[j][1].y = fmaf(u1, p1, s[j][1].y);
            }
        }
        #pragma unroll
        for (int j = 0; j < 8; ++j)
            #pragma unroll
            for (int a = 0; a < 2; ++a) {
                float2 r;
                r.x = tanh_fast(s[j][a].x);
                r.y = tanh_fast(s[j][a].y);
                *(float2*)(actions + (size_t)(cbase + j) * 2000 + a * 1000 + k0) = r;
            }
    }
}

// ---------------- main: hidden[k] = (P diag(lam^k)) @ y0 --------------------------
// Wave-specialized (4 compute / 4 store), rule-#20-fixed: inner rt loop FULLY
// UNROLLED so all register-array indices (ah/al/bh/bl, stage parity) are
// compile-time. Outer cg loop is runtime (addresses only). 32 barriers per side.
__global__ __launch_bounds__(512, 2) void k_hidden(const float* __restrict__ P,
                                                   const float* __restrict__ D,
                                                   const float* __restrict__ ws,
                                                   float* __restrict__ hidden) {
    int k = blockIdx.x;
    int tid = threadIdx.x;
    int wid = tid >> 6, lane = tid & 63;
    int l15 = lane & 15, lg = lane >> 4;

    __shared__ float stage[2][16 * ST_W];   // 2 x 16.6 KB
    __shared__ float lp_s[64];

    const u16* YH = (const u16*)(ws + OFF_HT);
    const u16* YL = YH + 131072;

    if (tid < 64) {
        float l = 1.0f - TSTEP * expf(D[tid]);
        lp_s[tid] = exp2f((float)k * log2f(l));
    }
    __syncthreads();

    float* outk = hidden + (size_t)k * 64 * NT;

    if (wid < 4) {
        // ---------------- compute waves ----------------
        bf16x8 ah[4][2], al[4][2];
        #pragma unroll
        for (int rt = 0; rt < 4; ++rt) {
            int r = rt * 16 + l15;
            #pragma unroll
            for (int kt = 0; kt < 2; ++kt) {
                int i0 = kt * 32 + lg * 8;
                #pragma unroll
                for (int j = 0; j < 8; ++j) {
                    float v = P[r * 64 + i0 + j] * lp_s[i0 + j];
                    u16 h, lo;
                    bsplit(v, h, lo);
                    ah[rt][kt][j] = (short)h;
                    al[rt][kt][j] = (short)lo;
                }
            }
        }
        bf16x8 bh[4][2], bl[4][2];
        #pragma unroll 1
        for (int cg = 0; cg < 8; ++cg) {
            // load B frags for this col-group (L2-hot; waits touch only B)
            #pragma unroll
            for (int q = 0; q < 4; ++q)
                #pragma unroll
                for (int kt = 0; kt < 2; ++kt) {
                    int ct_g = cg * 16 + wid * 4 + q;
                    int off = ((ct_g * 2 + kt) * 64 + lane) * 8;
                    bh[q][kt] = *(const bf16x8*)(YH + off);
                    bl[q][kt] = *(const bf16x8*)(YL + off);
                }
            #pragma unroll
            for (int rt = 0; rt < 4; ++rt) {       // FULLY UNROLLED -> static regs
                float* buf = stage[rt & 1];        // cg*4 even => parity = rt&1
                #pragma unroll
                for (int q = 0; q < 4; ++q) {
                    f32x4 acc = {0.f, 0.f, 0.f, 0.f};
                    #pragma unroll
                    for (int kt = 0; kt < 2; ++kt) {
                        acc = __builtin_amdgcn_mfma_f32_16x16x32_bf16(ah[rt][kt], bh[q][kt], acc, 0, 0, 0);
                        acc = __builtin_amdgcn_mfma_f32_16x16x32_bf16(al[rt][kt], bh[q][kt], acc, 0, 0, 0);
                        acc = __builtin_amdgcn_mfma_f32_16x16x32_bf16(ah[rt][kt], bl[q][kt], acc, 0, 0, 0);
                    }
                    int col = wid * 64 + q * 16 + l15;
                    #pragma unroll
                    for (int reg = 0; reg < 4; ++reg)
                        buf[(lg * 4 + reg) * ST_W + col] = acc[reg];
                }
                bar_lds();
            }
        }
        // store waves handle the final dump; compute waves exit
    } else {
        // ---------------- store waves ----------------
        int sw = wid - 4;
        #pragma unroll 1
        for (int p = 0; p < 32; ++p) {
            if (p > 0) {
                int pd = p - 1, cg = pd >> 2, rt = pd & 3;
                const float* buf = stage[pd & 1];
                #pragma unroll
                for (int r4 = 0; r4 < 4; ++r4) {
                    int row = sw * 4 + r4;
                    f32x4 v = *(const f32x4*)&buf[row * ST_W + lane * 4];
                    *(f32x4*)(outk + (size_t)(rt * 16 + row) * NT + cg * 256 + lane * 4) = v;
                }
            }
            bar_lds();
        }
        {   // epilogue: dump phase 31 (buf 1, cg 7, rt 3)
            const float* buf = stage[1];
            #pragma unroll
            for (int r4 = 0; r4 < 4; ++r4) {
                int row = sw * 4 + r4;
                f32x4 v = *(const f32x4*)&buf[row * ST_W + lane * 4];
                *(f32x4*)(outk + (size_t)(48 + row) * NT + 7 * 256 + lane * 4) = v;
            }
        }
    }
}

extern "C" void kernel_launch(void* const* d_in, const int* in_sizes, int n_in,
                              void* d_out, int out_size, void* d_ws, size_t ws_size,
                              hipStream_t stream) {
    const float* target = (const float*)d_in[0];
    const float* D      = (const float*)d_in[1];
    const float* P      = (const float*)d_in[2];
    const float* l1_w   = (const float*)d_in[3];
    const float* l1_b   = (const float*)d_in[4];
    const float* l2_w   = (const float*)d_in[5];
    const float* l2_b   = (const float*)d_in[6];
    const float* lm_w   = (const float*)d_in[7];
    const float* lm_b   = (const float*)d_in[8];
    float* ws = (float*)d_ws;
    float* actions = (float*)d_out;                  // 2048*2*1000
    float* hidden  = (float*)d_out + 4096000;        // 1000*64*2048

    hipLaunchKernelGGL(k_front,  dim3(256),  dim3(512), 0, stream,
                       target, l1_w, l1_b, l2_w, l2_b, lm_w, lm_b, D, P, ws, actions);
    hipLaunchKernelGGL(k_hidden, dim3(1000), dim3(512), 0, stream, P, D, ws, hidden);
}

// Round 18
// 183.336 us; speedup vs baseline: 15.1987x; 1.0158x over previous
//
#include <hip/hip_runtime.h>
#include <math.h>

#define NT 2048
#define HS 64
#define HNN 256
#define NSTEPS 1000
#define TSTEP 0.01f

typedef unsigned short u16;
typedef __attribute__((ext_vector_type(8))) short bf16x8;
typedef __attribute__((ext_vector_type(4))) float f32x4;

// ws: only the bf16 frag region is used
#define OFF_HT   148736    // YH (65536 floats worth) + YL

#define SW 68              // wave-private stage stride (floats); 16 rows x 68

// RNE f32 -> bf16 split: x ~= hi + lo (each bf16), err ~ 2^-18 |x|
__device__ inline void bsplit(float x, u16& hi, u16& lo) {
    unsigned u = __float_as_uint(x);
    unsigned r = (u + 0x7FFFu + ((u >> 16) & 1u)) >> 16;
    hi = (u16)r;
    float xh = __uint_as_float(r << 16);
    float d = x - xh;
    unsigned v = __float_as_uint(d);
    unsigned s = (v + 0x7FFFu + ((v >> 16) & 1u)) >> 16;
    lo = (u16)s;
}

__device__ inline float tanh_fast(float x) {
    float xc = fminf(fmaxf(x, -15.f), 15.f);
    float a = __builtin_amdgcn_exp2f(xc * 2.885390082f);   // e^{2x}
    return (a - 1.f) * __builtin_amdgcn_rcpf(a + 1.f);
}

// ---------------- k_front: 256 blocks x 512 thr, 8 cols/block (round-14 exact) ---
struct FrontSh {
    float Aug[64 * 73];        // [P | x0] 18.7 KB
    float shT[256 * 9];        // hT for 8 cols
    float y0s[64 * 9];
    float fvec[2][64];
    float tgt[8][2];
    float lam_s[64], l2l_s[64];
    float Q_s[128];
    float us[8 * 128];
};

__global__ __launch_bounds__(512) void k_front(const float* __restrict__ target,
                                               const float* __restrict__ l1_w,
                                               const float* __restrict__ l1_b,
                                               const float* __restrict__ l2_w,
                                               const float* __restrict__ l2_b,
                                               const float* __restrict__ lm_w,
                                               const float* __restrict__ lm_b,
                                               const float* __restrict__ D,
                                               const float* __restrict__ P,
                                               float* __restrict__ ws,
                                               float* __restrict__ actions) {
    __shared__ FrontSh sh;
    int ct = blockIdx.x;                 // 0..255
    int cbase = ct * 8;
    int tid = threadIdx.x;

    for (int idx = tid; idx < 4096; idx += 512) {
        int r = idx >> 6, c = idx & 63;
        sh.Aug[r * 73 + c] = P[r * 64 + c];
    }
    if (tid >= 448 && tid < 456) {
        int c = tid - 448;
        float2 tv = ((const float2*)target)[cbase + c];
        sh.tgt[c][0] = tv.x; sh.tgt[c][1] = tv.y;
    } else if (tid >= 256 && tid < 320) {
        int i = tid - 256;
        float l = 1.0f - TSTEP * expf(D[i]);
        sh.lam_s[i] = l;
        sh.l2l_s[i] = log2f(l);
    } else if (tid >= 320 && tid < 448) {
        int t = tid - 320;
        int a = t >> 6, i = t & 63;
        float s = 0.f;
        for (int r = 0; r < 64; ++r) s = fmaf(lm_w[a * 64 + r], P[r * 64 + i], s);
        sh.Q_s[t] = s;
    }
    __syncthreads();

    if (tid < 256) {
        float w0 = l1_w[2 * tid], w1 = l1_w[2 * tid + 1], bb = l1_b[tid];
        #pragma unroll
        for (int cc = 0; cc < 8; ++cc)
            sh.shT[tid * 9 + cc] =
                fmaxf(fmaf(w0, sh.tgt[cc][0], fmaf(w1, sh.tgt[cc][1], bb)), 0.f);
    }
    __syncthreads();

    int i = tid >> 3, c = tid & 7;
    {   // x0 -> Aug cols 64..71
        const float* l2wi = l2_w + i * 256;
        float a0 = l2_b[i], a1 = 0, a2 = 0, a3 = 0;
        #pragma unroll 4
        for (int j = 0; j < 256; j += 4) {
            a0 = fmaf(l2wi[j],     sh.shT[j * 9 + c],       a0);
            a1 = fmaf(l2wi[j + 1], sh.shT[(j + 1) * 9 + c], a1);
            a2 = fmaf(l2wi[j + 2], sh.shT[(j + 2) * 9 + c], a2);
            a3 = fmaf(l2wi[j + 3], sh.shT[(j + 3) * 9 + c], a3);
        }
        sh.Aug[i * 73 + 64 + c] = (a0 + a1) + (a2 + a3);
    }
    if (tid < 64) {
        float nv = sh.Aug[tid * 73];
        float pv = __shfl(nv, 0);
        sh.fvec[0][tid] = (tid == 0) ? 0.f : nv * __builtin_amdgcn_rcpf(pv);
    }
    __syncthreads();

    for (int t = 0; t < 64; ++t) {
        int par = t & 1;
        if (tid < 64) {
            int col0 = (t < 63) ? (t + 1) : 64;
            float f = sh.fvec[par][tid];
            float src = sh.Aug[t * 73 + col0];
            float nv = sh.Aug[tid * 73 + col0] - f * src;
            sh.Aug[tid * 73 + col0] = nv;
            if (t < 63) {
                float pv = __shfl(nv, t + 1);
                sh.fvec[par ^ 1][tid] = (tid == (t + 1)) ? 0.f
                                        : nv * __builtin_amdgcn_rcpf(pv);
            }
        } else {
            int w = (tid >> 6) - 1;
            int lane = tid & 63;
            float f = sh.fvec[par][lane];
            const float* rowp = sh.Aug + t * 73;
            float* rowr = sh.Aug + lane * 73;
            int pcnt = 62 - t;
            int smax = pcnt + 8;
            for (int s = 1 + w; s <= smax; s += 7) {
                int col = (s <= pcnt) ? (t + 1 + s) : (64 + (s - pcnt - 1));
                rowr[col] -= f * rowp[col];
            }
        }
        __syncthreads();
    }

    sh.y0s[i * 9 + c] = sh.Aug[i * 73 + 64 + c]
                        * __builtin_amdgcn_rcpf(sh.Aug[i * 73 + i]);
    __syncthreads();

    for (int idx = tid; idx < 1024; idx += 512) {
        int cgi = idx >> 7, t = idx & 127;
        sh.us[cgi * 128 + t] = sh.Q_s[t] * sh.y0s[(t & 63) * 9 + cgi];
    }
    if (tid < 128) {
        int kt = tid >> 6, lane = tid & 63;
        int c15 = lane & 15;
        if ((c15 >> 3) == (ct & 1)) {
            int cl = c15 & 7;
            int i0 = kt * 32 + (lane >> 4) * 8;
            u16* YH = (u16*)(ws + OFF_HT);
            u16* YL = YH + 131072;
            bf16x8 vh, vl;
            #pragma unroll
            for (int j = 0; j < 8; ++j) {
                u16 h, lo;
                bsplit(sh.y0s[(i0 + j) * 9 + cl], h, lo);
                vh[j] = (short)h; vl[j] = (short)lo;
            }
            int off = (((ct >> 1) * 2 + kt) * 64 + lane);
            *(bf16x8*)(YH + off * 8) = vh;
            *(bf16x8*)(YL + off * 8) = vl;
        }
    }
    __syncthreads();

    if (tid < 500) {
        int k0 = tid * 2;
        float b0 = lm_b[0], b1 = lm_b[1];
        float fk0 = (float)k0;
        float2 s[8][2];
        #pragma unroll
        for (int j = 0; j < 8; ++j) {
            s[j][0] = make_float2(b0, b0);
            s[j][1] = make_float2(b1, b1);
        }
        #pragma unroll 2
        for (int ii = 0; ii < 64; ++ii) {
            float p0 = __builtin_amdgcn_exp2f(fk0 * sh.l2l_s[ii]);
            float p1 = p0 * sh.lam_s[ii];
            #pragma unroll
            for (int j = 0; j < 8; ++j) {
                float u0 = sh.us[j * 128 + ii];
                float u1 = sh.us[j * 128 + 64 + ii];
                s[j][0].x = fmaf(u0, p0, s[j][0].x);
                s[j][0].y = fmaf(u0, p1, s[j][0].y);
                s[j][1].x = fmaf(u1, p0, s[j][1].x);
                s[j][1].y = fmaf(u1, p1, s[j][1].y);
            }
        }
        #pragma unroll
        for (int j = 0; j < 8; ++j)
            #pragma unroll
            for (int a = 0; a < 2; ++a) {
                float2 r;
                r.x = tanh_fast(s[j][a].x);
                r.y = tanh_fast(s[j][a].y);
                *(float2*)(actions + (size_t)(cbase + j) * 2000 + a * 1000 + k0) = r;
            }
    }
}

// ---------------- main: hidden[k] = (P diag(lam^k)) @ y0 --------------------------
// BARRIER-FREE, WAVE-PRIVATE: grid 2000 = (k, half). Each wave owns 128 cols x 64
// rows. ALL B-frags (32) + A-frags (16) preloaded in the prologue -> zero global
// loads after the first store -> zero vmcnt waits, store stream never pauses.
// Lane rearrangement (MFMA frag -> row-major) via a wave-private 16x68 LDS tile;
// only intra-wave lgkmcnt waits. All register indices compile-time (rule #20).
__global__ __launch_bounds__(512, 2) void k_hidden(const float* __restrict__ P,
                                                   const float* __restrict__ D,
                                                   const float* __restrict__ ws,
                                                   float* __restrict__ hidden) {
    int bid = blockIdx.x;
    int k = bid >> 1, half = bid & 1;
    int tid = threadIdx.x;
    int wid = tid >> 6, lane = tid & 63;
    int l15 = lane & 15, lg = lane >> 4;

    __shared__ float stage[8][16 * SW];   // 8 x 4.25 KB, wave-private
    __shared__ float lp_s[64];

    const u16* YH = (const u16*)(ws + OFF_HT);
    const u16* YL = YH + 131072;

    if (tid < 64) {
        float l = 1.0f - TSTEP * expf(D[tid]);
        lp_s[tid] = exp2f((float)k * log2f(l));
    }
    __syncthreads();     // only block-wide sync; before any stores

    // A fragments (P * lam^k)
    bf16x8 ah[4][2], al[4][2];
    #pragma unroll
    for (int rt = 0; rt < 4; ++rt) {
        int r = rt * 16 + l15;
        #pragma unroll
        for (int kt = 0; kt < 2; ++kt) {
            int i0 = kt * 32 + lg * 8;
            #pragma unroll
            for (int j = 0; j < 8; ++j) {
                float v = P[r * 64 + i0 + j] * lp_s[i0 + j];
                u16 h, lo;
                bsplit(v, h, lo);
                ah[rt][kt][j] = (short)h;
                al[rt][kt][j] = (short)lo;
            }
        }
    }
    // B fragments: this wave's 8 col-tiles, ALL preloaded (no loads after this)
    bf16x8 bh[8][2], bl[8][2];
    #pragma unroll
    for (int t = 0; t < 8; ++t)
        #pragma unroll
        for (int kt = 0; kt < 2; ++kt) {
            int ct_g = half * 64 + wid * 8 + t;
            int off = ((ct_g * 2 + kt) * 64 + lane) * 8;
            bh[t][kt] = *(const bf16x8*)(YH + off);
            bl[t][kt] = *(const bf16x8*)(YL + off);
        }

    float* outw = hidden + (size_t)k * 64 * NT + half * 1024 + wid * 128;
    float* st = stage[wid];

    #pragma unroll
    for (int rt = 0; rt < 4; ++rt) {
        #pragma unroll
        for (int qg = 0; qg < 2; ++qg) {
            #pragma unroll
            for (int q = 0; q < 4; ++q) {
                f32x4 acc = {0.f, 0.f, 0.f, 0.f};
                #pragma unroll
                for (int kt = 0; kt < 2; ++kt) {
                    acc = __builtin_amdgcn_mfma_f32_16x16x32_bf16(ah[rt][kt], bh[qg * 4 + q][kt], acc, 0, 0, 0);
                    acc = __builtin_amdgcn_mfma_f32_16x16x32_bf16(al[rt][kt], bh[qg * 4 + q][kt], acc, 0, 0, 0);
                    acc = __builtin_amdgcn_mfma_f32_16x16x32_bf16(ah[rt][kt], bl[qg * 4 + q][kt], acc, 0, 0, 0);
                }
                #pragma unroll
                for (int reg = 0; reg < 4; ++reg)
                    st[(lg * 4 + reg) * SW + q * 16 + l15] = acc[reg];
            }
            // read back row-major and stream out (1KB per instruction per wave)
            #pragma unroll
            for (int r4 = 0; r4 < 4; ++r4) {
                int row = r4 * 4 + (lane >> 4);
                f32x4 v = *(const f32x4*)&st[row * SW + (lane & 15) * 4];
                *(f32x4*)(outw + (size_t)(rt * 16 + row) * NT + qg * 64 + (lane & 15) * 4) = v;
            }
        }
    }
}

extern "C" void kernel_launch(void* const* d_in, const int* in_sizes, int n_in,
                              void* d_out, int out_size, void* d_ws, size_t ws_size,
                              hipStream_t stream) {
    const float* target = (const float*)d_in[0];
    const float* D      = (const float*)d_in[1];
    const float* P      = (const float*)d_in[2];
    const float* l1_w   = (const float*)d_in[3];
    const float* l1_b   = (const float*)d_in[4];
    const float* l2_w   = (const float*)d_in[5];
    const float* l2_b   = (const float*)d_in[6];
    const float* lm_w   = (const float*)d_in[7];
    const float* lm_b   = (const float*)d_in[8];
    float* ws = (float*)d_ws;
    float* actions = (float*)d_out;                  // 2048*2*1000
    float* hidden  = (float*)d_out + 4096000;        // 1000*64*2048

    hipLaunchKernelGGL(k_front,  dim3(256),  dim3(512), 0, stream,
                       target, l1_w, l1_b, l2_w, l2_b, lm_w, lm_b, D, P, ws, actions);
    hipLaunchKernelGGL(k_hidden, dim3(2000), dim3(512), 0, stream, P, D, ws, hidden);
}

// Round 19
// 166.572 us; speedup vs baseline: 16.7282x; 1.1006x over previous
//
#include <hip/hip_runtime.h>
#include <math.h>

#define NT 2048
#define HS 64
#define HNN 256
#define NSTEPS 1000
#define TSTEP 0.01f

typedef unsigned short u16;
typedef __attribute__((ext_vector_type(8))) short bf16x8;
typedef __attribute__((ext_vector_type(4))) float f32x4;

// ws: only the bf16 frag region is used
#define OFF_HT   148736    // YH (65536 floats worth) + YL

#define S_H 1028           // k_hidden LDS stage stride

// RNE f32 -> bf16 split: x ~= hi + lo (each bf16), err ~ 2^-18 |x|
__device__ inline void bsplit(float x, u16& hi, u16& lo) {
    unsigned u = __float_as_uint(x);
    unsigned r = (u + 0x7FFFu + ((u >> 16) & 1u)) >> 16;
    hi = (u16)r;
    float xh = __uint_as_float(r << 16);
    float d = x - xh;
    unsigned v = __float_as_uint(d);
    unsigned s = (v + 0x7FFFu + ((v >> 16) & 1u)) >> 16;
    lo = (u16)s;
}

__device__ inline void bar_lds() {
    asm volatile("s_waitcnt lgkmcnt(0)" ::: "memory");
    __builtin_amdgcn_s_barrier();
    asm volatile("" ::: "memory");
}

__device__ inline float tanh_fast(float x) {
    float xc = fminf(fmaxf(x, -15.f), 15.f);
    float a = __builtin_amdgcn_exp2f(xc * 2.885390082f);   // e^{2x}
    return (a - 1.f) * __builtin_amdgcn_rcpf(a + 1.f);
}

// ---------------- k_front: 256 blocks x 512 thr, 8 cols/block (round-14 exact) ---
struct FrontSh {
    float Aug[64 * 73];        // [P | x0] 18.7 KB
    float shT[256 * 9];        // hT for 8 cols
    float y0s[64 * 9];
    float fvec[2][64];
    float tgt[8][2];
    float lam_s[64], l2l_s[64];
    float Q_s[128];
    float us[8 * 128];
};

__global__ __launch_bounds__(512) void k_front(const float* __restrict__ target,
                                               const float* __restrict__ l1_w,
                                               const float* __restrict__ l1_b,
                                               const float* __restrict__ l2_w,
                                               const float* __restrict__ l2_b,
                                               const float* __restrict__ lm_w,
                                               const float* __restrict__ lm_b,
                                               const float* __restrict__ D,
                                               const float* __restrict__ P,
                                               float* __restrict__ ws,
                                               float* __restrict__ actions) {
    __shared__ FrontSh sh;
    int ct = blockIdx.x;                 // 0..255
    int cbase = ct * 8;
    int tid = threadIdx.x;

    for (int idx = tid; idx < 4096; idx += 512) {
        int r = idx >> 6, c = idx & 63;
        sh.Aug[r * 73 + c] = P[r * 64 + c];
    }
    if (tid >= 448 && tid < 456) {
        int c = tid - 448;
        float2 tv = ((const float2*)target)[cbase + c];
        sh.tgt[c][0] = tv.x; sh.tgt[c][1] = tv.y;
    } else if (tid >= 256 && tid < 320) {
        int i = tid - 256;
        float l = 1.0f - TSTEP * expf(D[i]);
        sh.lam_s[i] = l;
        sh.l2l_s[i] = log2f(l);
    } else if (tid >= 320 && tid < 448) {
        int t = tid - 320;
        int a = t >> 6, i = t & 63;
        float s = 0.f;
        for (int r = 0; r < 64; ++r) s = fmaf(lm_w[a * 64 + r], P[r * 64 + i], s);
        sh.Q_s[t] = s;
    }
    __syncthreads();

    if (tid < 256) {
        float w0 = l1_w[2 * tid], w1 = l1_w[2 * tid + 1], bb = l1_b[tid];
        #pragma unroll
        for (int cc = 0; cc < 8; ++cc)
            sh.shT[tid * 9 + cc] =
                fmaxf(fmaf(w0, sh.tgt[cc][0], fmaf(w1, sh.tgt[cc][1], bb)), 0.f);
    }
    __syncthreads();

    int i = tid >> 3, c = tid & 7;
    {   // x0 -> Aug cols 64..71
        const float* l2wi = l2_w + i * 256;
        float a0 = l2_b[i], a1 = 0, a2 = 0, a3 = 0;
        #pragma unroll 4
        for (int j = 0; j < 256; j += 4) {
            a0 = fmaf(l2wi[j],     sh.shT[j * 9 + c],       a0);
            a1 = fmaf(l2wi[j + 1], sh.shT[(j + 1) * 9 + c], a1);
            a2 = fmaf(l2wi[j + 2], sh.shT[(j + 2) * 9 + c], a2);
            a3 = fmaf(l2wi[j + 3], sh.shT[(j + 3) * 9 + c], a3);
        }
        sh.Aug[i * 73 + 64 + c] = (a0 + a1) + (a2 + a3);
    }
    if (tid < 64) {
        float nv = sh.Aug[tid * 73];
        float pv = __shfl(nv, 0);
        sh.fvec[0][tid] = (tid == 0) ? 0.f : nv * __builtin_amdgcn_rcpf(pv);
    }
    __syncthreads();

    for (int t = 0; t < 64; ++t) {
        int par = t & 1;
        if (tid < 64) {
            int col0 = (t < 63) ? (t + 1) : 64;
            float f = sh.fvec[par][tid];
            float src = sh.Aug[t * 73 + col0];
            float nv = sh.Aug[tid * 73 + col0] - f * src;
            sh.Aug[tid * 73 + col0] = nv;
            if (t < 63) {
                float pv = __shfl(nv, t + 1);
                sh.fvec[par ^ 1][tid] = (tid == (t + 1)) ? 0.f
                                        : nv * __builtin_amdgcn_rcpf(pv);
            }
        } else {
            int w = (tid >> 6) - 1;
            int lane = tid & 63;
            float f = sh.fvec[par][lane];
            const float* rowp = sh.Aug + t * 73;
            float* rowr = sh.Aug + lane * 73;
            int pcnt = 62 - t;
            int smax = pcnt + 8;
            for (int s = 1 + w; s <= smax; s += 7) {
                int col = (s <= pcnt) ? (t + 1 + s) : (64 + (s - pcnt - 1));
                rowr[col] -= f * rowp[col];
            }
        }
        __syncthreads();
    }

    sh.y0s[i * 9 + c] = sh.Aug[i * 73 + 64 + c]
                        * __builtin_amdgcn_rcpf(sh.Aug[i * 73 + i]);
    __syncthreads();

    for (int idx = tid; idx < 1024; idx += 512) {
        int cgi = idx >> 7, t = idx & 127;
        sh.us[cgi * 128 + t] = sh.Q_s[t] * sh.y0s[(t & 63) * 9 + cgi];
    }
    if (tid < 128) {
        int kt = tid >> 6, lane = tid & 63;
        int c15 = lane & 15;
        if ((c15 >> 3) == (ct & 1)) {
            int cl = c15 & 7;
            int i0 = kt * 32 + (lane >> 4) * 8;
            u16* YH = (u16*)(ws + OFF_HT);
            u16* YL = YH + 131072;
            bf16x8 vh, vl;
            #pragma unroll
            for (int j = 0; j < 8; ++j) {
                u16 h, lo;
                bsplit(sh.y0s[(i0 + j) * 9 + cl], h, lo);
                vh[j] = (short)h; vl[j] = (short)lo;
            }
            int off = (((ct >> 1) * 2 + kt) * 64 + lane);
            *(bf16x8*)(YH + off * 8) = vh;
            *(bf16x8*)(YL + off * 8) = vl;
        }
    }
    __syncthreads();

    if (tid < 500) {
        int k0 = tid * 2;
        float b0 = lm_b[0], b1 = lm_b[1];
        float fk0 = (float)k0;
        float2 s[8][2];
        #pragma unroll
        for (int j = 0; j < 8; ++j) {
            s[j][0] = make_float2(b0, b0);
            s[j][1] = make_float2(b1, b1);
        }
        #pragma unroll 2
        for (int ii = 0; ii < 64; ++ii) {
            float p0 = __builtin_amdgcn_exp2f(fk0 * sh.l2l_s[ii]);
            float p1 = p0 * sh.lam_s[ii];
            #pragma unroll
            for (int j = 0; j < 8; ++j) {
                float u0 = sh.us[j * 128 + ii];
                float u1 = sh.us[j * 128 + 64 + ii];
                s[j][0].x = fmaf(u0, p0, s[j][0].x);
                s[j][0].y = fmaf(u0, p1, s[j][0].y);
                s[j][1].x = fmaf(u1, p0, s[j][1].x);
                s[j][1].y = fmaf(u1, p1, s[j][1].y);
            }
        }
        #pragma unroll
        for (int j = 0; j < 8; ++j)
            #pragma unroll
            for (int a = 0; a < 2; ++a) {
                float2 r;
                r.x = tanh_fast(s[j][a].x);
                r.y = tanh_fast(s[j][a].y);
                *(float2*)(actions + (size_t)(cbase + j) * 2000 + a * 1000 + k0) = r;
            }
    }
}

// ---------------- main: hidden[k] = (P diag(lam^k)) @ y0 (round-14 exact) --------
__global__ __launch_bounds__(512, 2) void k_hidden(const float* __restrict__ P,
                                                   const float* __restrict__ D,
                                                   const float* __restrict__ ws,
                                                   float* __restrict__ hidden) {
    int k = blockIdx.x;
    int tid = threadIdx.x;
    int wid = tid >> 6, lane = tid & 63;
    int l15 = lane & 15, lg = lane >> 4;

    extern __shared__ float stage[];   // 16 * S_H floats = 65792 B
    __shared__ float lp_s[64];

    const u16* YH = (const u16*)(ws + OFF_HT);
    const u16* YL = YH + 131072;

    if (tid < 64) {
        float l = 1.0f - TSTEP * expf(D[tid]);
        lp_s[tid] = exp2f((float)k * log2f(l));
    }
    __syncthreads();

    bf16x8 ah[4][2], al[4][2];
    #pragma unroll
    for (int rt = 0; rt < 4; ++rt) {
        int r = rt * 16 + l15;
        #pragma unroll
        for (int kt = 0; kt < 2; ++kt) {
            int i0 = kt * 32 + lg * 8;
            #pragma unroll
            for (int j = 0; j < 8; ++j) {
                float v = P[r * 64 + i0 + j] * lp_s[i0 + j];
                u16 h, lo;
                bsplit(v, h, lo);
                ah[rt][kt][j] = (short)h;
                al[rt][kt][j] = (short)lo;
            }
        }
    }

    float* outk = hidden + (size_t)k * 64 * NT;

    #pragma unroll 1
    for (int half = 0; half < 2; ++half) {
        bf16x8 bh[8][2], bl[8][2];
        #pragma unroll
        for (int q = 0; q < 8; ++q)
            #pragma unroll
            for (int kt = 0; kt < 2; ++kt) {
                int ct_g = half * 64 + wid * 8 + q;
                int off = ((ct_g * 2 + kt) * 64 + lane) * 8;
                bh[q][kt] = *(const bf16x8*)(YH + off);
                bl[q][kt] = *(const bf16x8*)(YL + off);
            }
        #pragma unroll
        for (int rt = 0; rt < 4; ++rt) {
            #pragma unroll
            for (int q = 0; q < 8; ++q) {
                f32x4 acc = {0.f, 0.f, 0.f, 0.f};
                #pragma unroll
                for (int kt = 0; kt < 2; ++kt) {
                    acc = __builtin_amdgcn_mfma_f32_16x16x32_bf16(ah[rt][kt], bh[q][kt], acc, 0, 0, 0);
                    acc = __builtin_amdgcn_mfma_f32_16x16x32_bf16(al[rt][kt], bh[q][kt], acc, 0, 0, 0);
                    acc = __builtin_amdgcn_mfma_f32_16x16x32_bf16(ah[rt][kt], bl[q][kt], acc, 0, 0, 0);
                }
                int col = wid * 128 + q * 16 + l15;
                #pragma unroll
                for (int reg = 0; reg < 4; ++reg)
                    stage[(lg * 4 + reg) * S_H + col] = acc[reg];
            }
            bar_lds();
            #pragma unroll
            for (int it = 0; it < 8; ++it) {
                int f = it * 512 + tid;            // float4 index, 0..4095
                int r = f >> 8, c4 = f & 255;
                float4 v = *(const float4*)&stage[r * S_H + (c4 << 2)];
                *(float4*)(outk + (size_t)(rt * 16 + r) * NT + half * 1024 + (c4 << 2)) = v;
            }
            bar_lds();
        }
    }
}

extern "C" void kernel_launch(void* const* d_in, const int* in_sizes, int n_in,
                              void* d_out, int out_size, void* d_ws, size_t ws_size,
                              hipStream_t stream) {
    const float* target = (const float*)d_in[0];
    const float* D      = (const float*)d_in[1];
    const float* P      = (const float*)d_in[2];
    const float* l1_w   = (const float*)d_in[3];
    const float* l1_b   = (const float*)d_in[4];
    const float* l2_w   = (const float*)d_in[5];
    const float* l2_b   = (const float*)d_in[6];
    const float* lm_w   = (const float*)d_in[7];
    const float* lm_b   = (const float*)d_in[8];
    float* ws = (float*)d_ws;
    float* actions = (float*)d_out;                  // 2048*2*1000
    float* hidden  = (float*)d_out + 4096000;        // 1000*64*2048

    hipFuncSetAttribute((const void*)k_hidden,
                        hipFuncAttributeMaxDynamicSharedMemorySize, 16 * S_H * 4);

    hipLaunchKernelGGL(k_front,  dim3(256),  dim3(512), 0, stream,
                       target, l1_w, l1_b, l2_w, l2_b, lm_w, lm_b, D, P, ws, actions);
    hipLaunchKernelGGL(k_hidden, dim3(1000), dim3(512), 16 * S_H * 4, stream, P, D, ws, hidden);
}